// Round 1
// baseline (330.758 us; speedup 1.0000x reference)
//
#include <hip/hip_runtime.h>
#include <hip/hip_bf16.h>
#include <math.h>

// Problem constants (match reference)
constexpr int B_ = 512;
constexpr int N_ = 128;
constexpr int D_ = 512;
constexpr float TEMP_INV = 1.0f / 0.07f;
constexpr float NEG_INF_ = -1e9f;
constexpr float EPS_ = 1e-12f;

// Workspace layout (in floats)
constexpr size_t OFF_TN     = 0;                        // B*D   normalized text
constexpr size_t OFF_GTV    = OFF_TN + (size_t)B_ * D_; // B*D   normalized gt visuals
constexpr size_t OFF_POS    = OFF_GTV + (size_t)B_ * D_;// B     pos_sim
constexpr size_t OFF_LIN    = OFF_POS + B_;             // B*N   in-sample logits
constexpr size_t OFF_LB     = OFF_LIN + (size_t)B_ * N_;// B*B   in-batch logits
constexpr size_t OFF_SV     = OFF_LB + (size_t)B_ * B_; // B     sample_valid (int)
constexpr size_t OFF_V8     = OFF_SV + B_;              // B*N bytes (B*N/4 floats)
constexpr size_t OFF_SCAL   = OFF_V8 + (size_t)B_ * N_ / 4; // flags[2], n_valid, total, acc

// ---------------------------------------------------------------------------
// Detect how the bool `valid` array was uploaded: float32 / uint8 / int32.
// For 0/1 data the bit patterns are unambiguous:
//  - any word == 0x3f800000  -> float32 (1.0f); impossible for u8 0/1 or i32 0/1
//  - else any bits in [8,32) -> uint8 bytes (packed bools)
//  - else                    -> int32
__global__ void detect_kernel(const unsigned int* valid_words, int* flags) {
    int lf = 0, lb = 0;
    for (int i = threadIdx.x; i < (B_ * N_) / 4; i += blockDim.x) {
        unsigned int v = valid_words[i];
        if (v == 0x3f800000u) lf = 1;
        if (v & 0xffffff00u) lb = 1;
    }
    if (lf) atomicOr(&flags[0], 1);
    if (lb) atomicOr(&flags[1], 1);
}

__global__ void convert_valid_kernel(const void* raw, const int* flags, unsigned char* out) {
    int i = blockIdx.x * blockDim.x + threadIdx.x;
    if (i >= B_ * N_) return;
    unsigned char v;
    if (flags[0])      v = (((const float*)raw)[i] != 0.0f) ? 1 : 0;
    else if (flags[1]) v = (((const unsigned char*)raw)[i] != 0) ? 1 : 0;
    else               v = (((const int*)raw)[i] != 0) ? 1 : 0;
    out[i] = v;
}

__device__ __forceinline__ float wave_sum(float v) {
    for (int off = 32; off; off >>= 1) v += __shfl_xor(v, off);
    return v;
}

// ---------------------------------------------------------------------------
// Normalize text embeddings. One block (256 thr) per row; 2 elems/thread.
__global__ __launch_bounds__(256) void norm_text_kernel(const float* __restrict__ text,
                                                        float* __restrict__ tn) {
    int b = blockIdx.x;
    const float* row = text + (size_t)b * D_;
    float x0 = row[threadIdx.x];
    float x1 = row[threadIdx.x + 256];
    float ss = x0 * x0 + x1 * x1;
    ss = wave_sum(ss);
    __shared__ float red[4];
    __shared__ float invsh;
    int wave = threadIdx.x >> 6, lane = threadIdx.x & 63;
    if (lane == 0) red[wave] = ss;
    __syncthreads();
    if (threadIdx.x == 0) {
        float s = red[0] + red[1] + red[2] + red[3];
        invsh = 1.0f / fmaxf(sqrtf(s), EPS_);
    }
    __syncthreads();
    float inv = invsh;
    tn[(size_t)b * D_ + threadIdx.x]       = x0 * inv;
    tn[(size_t)b * D_ + threadIdx.x + 256] = x1 * inv;
}

// ---------------------------------------------------------------------------
// Per-sample GT visual: normalized row, pos_sim, sample_valid, n_valid.
__global__ __launch_bounds__(256) void gt_kernel(const float* __restrict__ visual,
                                                 const float* __restrict__ tn,
                                                 const int* __restrict__ gt,
                                                 const unsigned char* __restrict__ valid8,
                                                 float* __restrict__ gtv,
                                                 float* __restrict__ pos_sim,
                                                 int* __restrict__ svalid,
                                                 int* __restrict__ n_valid) {
    int b = blockIdx.x;
    int g = gt[b];
    int gc = min(max(g, 0), N_ - 1);
    const float* vrow = visual + ((size_t)b * N_ + gc) * D_;
    const float* trow = tn + (size_t)b * D_;
    float v0 = vrow[threadIdx.x], v1 = vrow[threadIdx.x + 256];
    float t0 = trow[threadIdx.x], t1 = trow[threadIdx.x + 256];
    float ssv = v0 * v0 + v1 * v1;
    float dot = t0 * v0 + t1 * v1;
    ssv = wave_sum(ssv);
    dot = wave_sum(dot);
    __shared__ float rs[4], rd[4];
    __shared__ float invsh;
    int wave = threadIdx.x >> 6, lane = threadIdx.x & 63;
    if (lane == 0) { rs[wave] = ssv; rd[wave] = dot; }
    __syncthreads();
    if (threadIdx.x == 0) {
        float s = rs[0] + rs[1] + rs[2] + rs[3];
        float d = rd[0] + rd[1] + rd[2] + rd[3];
        float inv = 1.0f / fmaxf(sqrtf(s), EPS_);
        invsh = inv;
        pos_sim[b] = d * inv * TEMP_INV;
        int sv = (g >= 0 && g < N_ && valid8[(size_t)b * N_ + gc]) ? 1 : 0;
        svalid[b] = sv;
        if (sv) atomicAdd(n_valid, 1);
    }
    __syncthreads();
    float inv = invsh;
    gtv[(size_t)b * D_ + threadIdx.x]       = v0 * inv;
    gtv[(size_t)b * D_ + threadIdx.x + 256] = v1 * inv;
}

// ---------------------------------------------------------------------------
// In-sample logits: block per b; 4 waves; each wave does full D=512 rows.
// Fuses visual-row normalization (sumsq) into the same global read.
__global__ __launch_bounds__(256) void insample_kernel(const float* __restrict__ visual,
                                                       const float* __restrict__ tn,
                                                       const int* __restrict__ gt,
                                                       const unsigned char* __restrict__ valid8,
                                                       float* __restrict__ logits_in) {
    int b = blockIdx.x;
    __shared__ float tsh[D_];
    tsh[threadIdx.x]       = tn[(size_t)b * D_ + threadIdx.x];
    tsh[threadIdx.x + 256] = tn[(size_t)b * D_ + threadIdx.x + 256];
    __syncthreads();
    int g = gt[b];
    int gc = min(max(g, 0), N_ - 1);
    int wave = threadIdx.x >> 6, lane = threadIdx.x & 63;
    float4 tA = *(const float4*)&tsh[lane * 8];
    float4 tC = *(const float4*)&tsh[lane * 8 + 4];
    for (int n = wave; n < N_; n += 4) {
        const float* vrow = visual + ((size_t)b * N_ + n) * D_;
        float4 a = *(const float4*)&vrow[lane * 8];
        float4 c = *(const float4*)&vrow[lane * 8 + 4];
        float ss = a.x*a.x + a.y*a.y + a.z*a.z + a.w*a.w
                 + c.x*c.x + c.y*c.y + c.z*c.z + c.w*c.w;
        float dt = tA.x*a.x + tA.y*a.y + tA.z*a.z + tA.w*a.w
                 + tC.x*c.x + tC.y*c.y + tC.z*c.z + tC.w*c.w;
        ss = wave_sum(ss);
        dt = wave_sum(dt);
        if (lane == 0) {
            bool m = valid8[(size_t)b * N_ + n] && (n != gc);
            float inv = 1.0f / fmaxf(sqrtf(ss), EPS_);
            logits_in[(size_t)b * N_ + n] = m ? dt * inv * TEMP_INV : NEG_INF_;
        }
    }
}

// ---------------------------------------------------------------------------
// In-batch logits: sims_batch[b][j] = tn[b]·gtv[j]/T, masked. L2-resident.
__global__ __launch_bounds__(256) void batch_kernel(const float* __restrict__ gtv,
                                                    const float* __restrict__ tn,
                                                    const int* __restrict__ svalid,
                                                    float* __restrict__ logits_b) {
    int b = blockIdx.x;
    __shared__ float tsh[D_];
    tsh[threadIdx.x]       = tn[(size_t)b * D_ + threadIdx.x];
    tsh[threadIdx.x + 256] = tn[(size_t)b * D_ + threadIdx.x + 256];
    __syncthreads();
    int wave = threadIdx.x >> 6, lane = threadIdx.x & 63;
    float4 tA = *(const float4*)&tsh[lane * 8];
    float4 tC = *(const float4*)&tsh[lane * 8 + 4];
    for (int j = wave; j < B_; j += 4) {
        const float* vrow = gtv + (size_t)j * D_;
        float4 a = *(const float4*)&vrow[lane * 8];
        float4 c = *(const float4*)&vrow[lane * 8 + 4];
        float dt = tA.x*a.x + tA.y*a.y + tA.z*a.z + tA.w*a.w
                 + tC.x*c.x + tC.y*c.y + tC.z*c.z + tC.w*c.w;
        dt = wave_sum(dt);
        if (lane == 0) {
            bool m = svalid[j] && (j != b);
            logits_b[(size_t)b * B_ + j] = m ? dt * TEMP_INV : NEG_INF_;
        }
    }
}

// ---------------------------------------------------------------------------
// Per-row logsumexp over [pos, in-sample negs, batch negs]; atomics for sums.
__global__ __launch_bounds__(256) void final_kernel(const float* __restrict__ logits_in,
                                                    const float* __restrict__ logits_b,
                                                    const float* __restrict__ pos_sim,
                                                    const int* __restrict__ svalid,
                                                    float* __restrict__ accum /*[0]=total,[1]=acc*/) {
    int b = blockIdx.x;
    float pos = pos_sim[b];
    // pass 1: max over negatives
    float lmax = NEG_INF_;
    for (int i = threadIdx.x; i < N_ + B_; i += 256) {
        float x = (i < N_) ? logits_in[(size_t)b * N_ + i]
                           : logits_b[(size_t)b * B_ + (i - N_)];
        lmax = fmaxf(lmax, x);
    }
    for (int off = 32; off; off >>= 1) lmax = fmaxf(lmax, __shfl_xor(lmax, off));
    __shared__ float rmax[4];
    __shared__ float maxneg_sh;
    int wave = threadIdx.x >> 6, lane = threadIdx.x & 63;
    if (lane == 0) rmax[wave] = lmax;
    __syncthreads();
    if (threadIdx.x == 0)
        maxneg_sh = fmaxf(fmaxf(rmax[0], rmax[1]), fmaxf(rmax[2], rmax[3]));
    __syncthreads();
    float maxneg = maxneg_sh;
    float m = fmaxf(maxneg, pos);
    // pass 2: sum exp
    float lsum = 0.0f;
    for (int i = threadIdx.x; i < N_ + B_; i += 256) {
        float x = (i < N_) ? logits_in[(size_t)b * N_ + i]
                           : logits_b[(size_t)b * B_ + (i - N_)];
        lsum += expf(x - m);
    }
    lsum = wave_sum(lsum);
    __shared__ float rsum[4];
    if (lane == 0) rsum[wave] = lsum;
    __syncthreads();
    if (threadIdx.x == 0) {
        float s = rsum[0] + rsum[1] + rsum[2] + rsum[3] + expf(pos - m);
        float lse = m + logf(s);
        float loss = lse - pos;
        bool has_neg = maxneg > -1e8f;
        bool contrib = (svalid[b] != 0) && has_neg;
        if (contrib) {
            atomicAdd(&accum[0], loss);
            if (pos >= maxneg) atomicAdd(&accum[1], 1.0f);
        }
    }
}

__global__ void finalize_kernel(const float* __restrict__ accum,
                                const int* __restrict__ n_valid,
                                float* __restrict__ out) {
    if (threadIdx.x == 0 && blockIdx.x == 0) {
        float denom = fmaxf((float)(*n_valid), 1.0f);
        out[0] = accum[0] / denom;
        out[1] = accum[1] / denom;
    }
}

// ---------------------------------------------------------------------------
extern "C" void kernel_launch(void* const* d_in, const int* in_sizes, int n_in,
                              void* d_out, int out_size, void* d_ws, size_t ws_size,
                              hipStream_t stream) {
    const float* text   = (const float*)d_in[0];
    const float* visual = (const float*)d_in[1];
    const void*  valid  = d_in[2];
    const int*   gt     = (const int*)d_in[3];
    float* out = (float*)d_out;

    float* wsf = (float*)d_ws;
    float* tn      = wsf + OFF_TN;
    float* gtv     = wsf + OFF_GTV;
    float* pos_sim = wsf + OFF_POS;
    float* lin     = wsf + OFF_LIN;
    float* lb      = wsf + OFF_LB;
    int*   svalid  = (int*)(wsf + OFF_SV);
    unsigned char* valid8 = (unsigned char*)(wsf + OFF_V8);
    int*   flags   = (int*)(wsf + OFF_SCAL);       // [0],[1]
    int*   n_valid = (int*)(wsf + OFF_SCAL) + 2;   // [2]
    float* accum   = (wsf + OFF_SCAL) + 3;         // [3],[4]

    // zero scalar block (flags, n_valid, accumulators)
    hipMemsetAsync(wsf + OFF_SCAL, 0, 5 * sizeof(float), stream);

    detect_kernel<<<1, 256, 0, stream>>>((const unsigned int*)valid, flags);
    convert_valid_kernel<<<(B_ * N_ + 255) / 256, 256, 0, stream>>>(valid, flags, valid8);
    norm_text_kernel<<<B_, 256, 0, stream>>>(text, tn);
    gt_kernel<<<B_, 256, 0, stream>>>(visual, tn, gt, valid8, gtv, pos_sim, svalid, n_valid);
    insample_kernel<<<B_, 256, 0, stream>>>(visual, tn, gt, valid8, lin);
    batch_kernel<<<B_, 256, 0, stream>>>(gtv, tn, svalid, lb);
    final_kernel<<<B_, 256, 0, stream>>>(lin, lb, pos_sim, svalid, accum);
    finalize_kernel<<<1, 64, 0, stream>>>(accum, n_valid, out);
}

// Round 2
// 304.149 us; speedup vs baseline: 1.0875x; 1.0875x over previous
//
#include <hip/hip_runtime.h>
#include <hip/hip_bf16.h>
#include <math.h>

// Problem constants (match reference)
constexpr int B_ = 512;
constexpr int N_ = 128;
constexpr int D_ = 512;
constexpr float TEMP_INV = 1.0f / 0.07f;
constexpr float NEG_INF_ = -1e9f;
constexpr float EPS_ = 1e-12f;

// Workspace layout (in floats)
constexpr size_t OFF_TN   = 0;                          // B*D normalized text
constexpr size_t OFF_GTV  = OFF_TN + (size_t)B_ * D_;   // B*D normalized gt visuals
constexpr size_t OFF_POS  = OFF_GTV + (size_t)B_ * D_;  // B   pos_sim
constexpr size_t OFF_LIN  = OFF_POS + B_;               // B*N in-sample logits
constexpr size_t OFF_SV   = OFF_LIN + (size_t)B_ * N_;  // B   sample_valid (int)
constexpr size_t OFF_V8   = OFF_SV + B_;                // B*N bytes as floats
constexpr size_t OFF_SCAL = OFF_V8 + (size_t)B_ * N_ / 4; // flags[2], n_valid, total, acc

__device__ __forceinline__ float wave_sum(float v) {
    for (int off = 32; off; off >>= 1) v += __shfl_xor(v, off);
    return v;
}

// ---------------------------------------------------------------------------
// Detect `valid` upload dtype: float32 / uint8 / int32. Scan only the first
// 64 KB (16384 words) — safe for all three dtypes (uint8 buffer is exactly
// 64 KB). 0/1 data makes the patterns unambiguous:
//   word == 0x3f800000 -> float32 (1.0f)
//   else bits in [8,32) set -> uint8 (packed bytes, e.g. 0x01010101)
//   else -> int32
__global__ __launch_bounds__(256) void detect_kernel(const unsigned int* __restrict__ w,
                                                     int* __restrict__ flags) {
    int i = blockIdx.x * blockDim.x + threadIdx.x;   // 64 blocks * 256 = 16384
    unsigned int v = w[i];
    int lf = (v == 0x3f800000u) ? 1 : 0;
    int lb = (v & 0xffffff00u) ? 1 : 0;
    unsigned long long mf = __ballot(lf);
    unsigned long long mb = __ballot(lb);
    int lane = threadIdx.x & 63;
    if (lane == 0) {
        if (mf) atomicOr(&flags[0], 1);
        if (mb) atomicOr(&flags[1], 1);
    }
}

__global__ __launch_bounds__(256) void convert_valid_kernel(const void* __restrict__ raw,
                                                            const int* __restrict__ flags,
                                                            unsigned char* __restrict__ out) {
    int i = blockIdx.x * blockDim.x + threadIdx.x;
    if (i >= B_ * N_) return;
    unsigned char v;
    if (flags[0])      v = (((const float*)raw)[i] != 0.0f) ? 1 : 0;
    else if (flags[1]) v = (((const unsigned char*)raw)[i] != 0) ? 1 : 0;
    else               v = (((const int*)raw)[i] != 0) ? 1 : 0;
    out[i] = v;
}

// ---------------------------------------------------------------------------
// Phase A (per b): normalize text row, normalize GT visual row, pos_sim,
// sample_valid, n_valid. One block per b.
__global__ __launch_bounds__(256) void phaseA_kernel(const float* __restrict__ text,
                                                     const float* __restrict__ visual,
                                                     const int* __restrict__ gt,
                                                     const unsigned char* __restrict__ valid8,
                                                     float* __restrict__ tn,
                                                     float* __restrict__ gtv,
                                                     float* __restrict__ pos_sim,
                                                     int* __restrict__ svalid,
                                                     int* __restrict__ n_valid) {
    int b = blockIdx.x;
    int tid = threadIdx.x;
    int g = gt[b];
    int gc = min(max(g, 0), N_ - 1);
    const float* trow = text + (size_t)b * D_;
    const float* vrow = visual + ((size_t)b * N_ + gc) * D_;
    float t0 = trow[tid], t1 = trow[tid + 256];
    float v0 = vrow[tid], v1 = vrow[tid + 256];
    float sst = t0 * t0 + t1 * t1;
    float ssv = v0 * v0 + v1 * v1;
    float dot = t0 * v0 + t1 * v1;
    sst = wave_sum(sst);
    ssv = wave_sum(ssv);
    dot = wave_sum(dot);
    __shared__ float r0[4], r1[4], r2[4];
    __shared__ float invt_sh, invv_sh;
    int wave = tid >> 6, lane = tid & 63;
    if (lane == 0) { r0[wave] = sst; r1[wave] = ssv; r2[wave] = dot; }
    __syncthreads();
    if (tid == 0) {
        float st = r0[0] + r0[1] + r0[2] + r0[3];
        float sv = r1[0] + r1[1] + r1[2] + r1[3];
        float d  = r2[0] + r2[1] + r2[2] + r2[3];
        float invt = 1.0f / fmaxf(sqrtf(st), EPS_);
        float invv = 1.0f / fmaxf(sqrtf(sv), EPS_);
        invt_sh = invt;
        invv_sh = invv;
        pos_sim[b] = d * invt * invv * TEMP_INV;
        int s = (g >= 0 && g < N_ && valid8[(size_t)b * N_ + gc]) ? 1 : 0;
        svalid[b] = s;
        if (s) atomicAdd(n_valid, 1);
    }
    __syncthreads();
    float invt = invt_sh, invv = invv_sh;
    tn [(size_t)b * D_ + tid]       = t0 * invt;
    tn [(size_t)b * D_ + tid + 256] = t1 * invt;
    gtv[(size_t)b * D_ + tid]       = v0 * invv;
    gtv[(size_t)b * D_ + tid + 256] = v1 * invv;
}

// ---------------------------------------------------------------------------
// In-sample logits: block per b; 4 waves; each wave-dot covers full D=512.
// Fuses visual-row normalization into the single 134 MB streaming read.
__global__ __launch_bounds__(256) void insample_kernel(const float* __restrict__ visual,
                                                       const float* __restrict__ tn,
                                                       const int* __restrict__ gt,
                                                       const unsigned char* __restrict__ valid8,
                                                       float* __restrict__ logits_in) {
    int b = blockIdx.x;
    __shared__ float tsh[D_];
    tsh[threadIdx.x]       = tn[(size_t)b * D_ + threadIdx.x];
    tsh[threadIdx.x + 256] = tn[(size_t)b * D_ + threadIdx.x + 256];
    __syncthreads();
    int g = gt[b];
    int gc = min(max(g, 0), N_ - 1);
    int wave = threadIdx.x >> 6, lane = threadIdx.x & 63;
    float4 tA = *(const float4*)&tsh[lane * 8];
    float4 tC = *(const float4*)&tsh[lane * 8 + 4];
    for (int n = wave; n < N_; n += 4) {
        const float* vrow = visual + ((size_t)b * N_ + n) * D_;
        float4 a = *(const float4*)&vrow[lane * 8];
        float4 c = *(const float4*)&vrow[lane * 8 + 4];
        float ss = a.x*a.x + a.y*a.y + a.z*a.z + a.w*a.w
                 + c.x*c.x + c.y*c.y + c.z*c.z + c.w*c.w;
        float dt = tA.x*a.x + tA.y*a.y + tA.z*a.z + tA.w*a.w
                 + tC.x*c.x + tC.y*c.y + tC.z*c.z + tC.w*c.w;
        ss = wave_sum(ss);
        dt = wave_sum(dt);
        if (lane == 0) {
            bool m = valid8[(size_t)b * N_ + n] && (n != gc);
            float inv = 1.0f / fmaxf(sqrtf(ss), EPS_);
            logits_in[(size_t)b * N_ + n] = m ? dt * inv * TEMP_INV : NEG_INF_;
        }
    }
}

// ---------------------------------------------------------------------------
// Batch logits + logsumexp, fused. One block per TWO rows b (halves gtv
// re-read traffic). Batch-logit rows live only in LDS.
__device__ __forceinline__ void lse_row(int b, const float* __restrict__ logits_in,
                                        const float* lbsh,
                                        const float* __restrict__ pos_sim,
                                        const int* __restrict__ svalid,
                                        float* __restrict__ accum,
                                        float* red, float* sh1) {
    int tid = threadIdx.x;
    int wave = tid >> 6, lane = tid & 63;
    float pos = pos_sim[b];
    // max over negatives: 128 in-sample (global) + 512 batch (LDS)
    float lmax = NEG_INF_;
    if (tid < N_) lmax = logits_in[(size_t)b * N_ + tid];
    lmax = fmaxf(lmax, lbsh[tid]);
    lmax = fmaxf(lmax, lbsh[tid + 256]);
    for (int off = 32; off; off >>= 1) lmax = fmaxf(lmax, __shfl_xor(lmax, off));
    if (lane == 0) red[wave] = lmax;
    __syncthreads();
    if (tid == 0) sh1[0] = fmaxf(fmaxf(red[0], red[1]), fmaxf(red[2], red[3]));
    __syncthreads();
    float maxneg = sh1[0];
    float m = fmaxf(maxneg, pos);
    float lsum = 0.0f;
    if (tid < N_) lsum = __expf(logits_in[(size_t)b * N_ + tid] - m);
    lsum += __expf(lbsh[tid] - m) + __expf(lbsh[tid + 256] - m);
    lsum = wave_sum(lsum);
    __syncthreads();          // red[] reuse
    if (lane == 0) red[wave] = lsum;
    __syncthreads();
    if (tid == 0) {
        float s = red[0] + red[1] + red[2] + red[3] + __expf(pos - m);
        float lse = m + logf(s);
        float loss = lse - pos;
        bool has_neg = maxneg > -1e8f;
        bool contrib = (svalid[b] != 0) && has_neg;
        if (contrib) {
            atomicAdd(&accum[0], loss);
            if (pos >= maxneg) atomicAdd(&accum[1], 1.0f);
        }
    }
    __syncthreads();
}

__global__ __launch_bounds__(256) void batchfinal_kernel(const float* __restrict__ gtv,
                                                         const float* __restrict__ tn,
                                                         const float* __restrict__ logits_in,
                                                         const float* __restrict__ pos_sim,
                                                         const int* __restrict__ svalid,
                                                         float* __restrict__ accum) {
    int b0 = blockIdx.x * 2;
    int b1 = b0 + 1;
    __shared__ float lb0[B_], lb1[B_];   // 4 KB batch-logit rows
    __shared__ float red[4], sh1[1];
    int wave = threadIdx.x >> 6, lane = threadIdx.x & 63;
    const float* t0row = tn + (size_t)b0 * D_;
    const float* t1row = tn + (size_t)b1 * D_;
    float4 t0A = *(const float4*)&t0row[lane * 8];
    float4 t0C = *(const float4*)&t0row[lane * 8 + 4];
    float4 t1A = *(const float4*)&t1row[lane * 8];
    float4 t1C = *(const float4*)&t1row[lane * 8 + 4];
    for (int j = wave; j < B_; j += 4) {
        const float* grow = gtv + (size_t)j * D_;
        float4 a = *(const float4*)&grow[lane * 8];
        float4 c = *(const float4*)&grow[lane * 8 + 4];
        float d0 = t0A.x*a.x + t0A.y*a.y + t0A.z*a.z + t0A.w*a.w
                 + t0C.x*c.x + t0C.y*c.y + t0C.z*c.z + t0C.w*c.w;
        float d1 = t1A.x*a.x + t1A.y*a.y + t1A.z*a.z + t1A.w*a.w
                 + t1C.x*c.x + t1C.y*c.y + t1C.z*c.z + t1C.w*c.w;
        d0 = wave_sum(d0);
        d1 = wave_sum(d1);
        if (lane == 0) {
            int sv = svalid[j];
            lb0[j] = (sv && j != b0) ? d0 * TEMP_INV : NEG_INF_;
            lb1[j] = (sv && j != b1) ? d1 * TEMP_INV : NEG_INF_;
        }
    }
    __syncthreads();
    lse_row(b0, logits_in, lb0, pos_sim, svalid, accum, red, sh1);
    lse_row(b1, logits_in, lb1, pos_sim, svalid, accum, red, sh1);
}

__global__ void finalize_kernel(const float* __restrict__ accum,
                                const int* __restrict__ n_valid,
                                float* __restrict__ out) {
    if (threadIdx.x == 0 && blockIdx.x == 0) {
        float denom = fmaxf((float)(*n_valid), 1.0f);
        out[0] = accum[0] / denom;
        out[1] = accum[1] / denom;
    }
}

// ---------------------------------------------------------------------------
extern "C" void kernel_launch(void* const* d_in, const int* in_sizes, int n_in,
                              void* d_out, int out_size, void* d_ws, size_t ws_size,
                              hipStream_t stream) {
    const float* text   = (const float*)d_in[0];
    const float* visual = (const float*)d_in[1];
    const void*  valid  = d_in[2];
    const int*   gt     = (const int*)d_in[3];
    float* out = (float*)d_out;

    float* wsf = (float*)d_ws;
    float* tn      = wsf + OFF_TN;
    float* gtv     = wsf + OFF_GTV;
    float* pos_sim = wsf + OFF_POS;
    float* lin     = wsf + OFF_LIN;
    int*   svalid  = (int*)(wsf + OFF_SV);
    unsigned char* valid8 = (unsigned char*)(wsf + OFF_V8);
    int*   flags   = (int*)(wsf + OFF_SCAL);       // [0],[1]
    int*   n_valid = (int*)(wsf + OFF_SCAL) + 2;   // [2]
    float* accum   = (wsf + OFF_SCAL) + 3;         // [3],[4]

    hipMemsetAsync(wsf + OFF_SCAL, 0, 5 * sizeof(float), stream);

    detect_kernel<<<64, 256, 0, stream>>>((const unsigned int*)valid, flags);
    convert_valid_kernel<<<(B_ * N_ + 255) / 256, 256, 0, stream>>>(valid, flags, valid8);
    phaseA_kernel<<<B_, 256, 0, stream>>>(text, visual, gt, valid8, tn, gtv, pos_sim, svalid, n_valid);
    insample_kernel<<<B_, 256, 0, stream>>>(visual, tn, gt, valid8, lin);
    batchfinal_kernel<<<B_ / 2, 256, 0, stream>>>(gtv, tn, lin, pos_sim, svalid, accum);
    finalize_kernel<<<1, 64, 0, stream>>>(accum, n_valid, out);
}

// Round 3
// 235.328 us; speedup vs baseline: 1.4055x; 1.2924x over previous
//
#include <hip/hip_runtime.h>
#include <hip/hip_bf16.h>
#include <math.h>

// Problem constants (match reference)
constexpr int B_ = 512;
constexpr int N_ = 128;
constexpr int D_ = 512;
constexpr float TEMP_INV = 1.0f / 0.07f;
constexpr float NEG_INF_ = -1e9f;
constexpr float EPS_ = 1e-12f;

// Workspace layout (in floats)
constexpr size_t OFF_TN   = 0;                          // B*D normalized text
constexpr size_t OFF_GTV  = OFF_TN + (size_t)B_ * D_;   // B*D normalized gt visuals
constexpr size_t OFF_POS  = OFF_GTV + (size_t)B_ * D_;  // B   pos_sim
constexpr size_t OFF_LIN  = OFF_POS + B_;               // B*N in-sample logits
constexpr size_t OFF_LB   = OFF_LIN + (size_t)B_ * N_;  // B*B batch logits
constexpr size_t OFF_SV   = OFF_LB + (size_t)B_ * B_;   // B   sample_valid (int)
constexpr size_t OFF_V8   = OFF_SV + B_;                // B*N bytes as floats
constexpr size_t OFF_SCAL = OFF_V8 + (size_t)B_ * N_ / 4; // flags[2], n_valid, total, acc

__device__ __forceinline__ float wave_sum(float v) {
    for (int off = 32; off; off >>= 1) v += __shfl_xor(v, off);
    return v;
}

// ---------------------------------------------------------------------------
// Detect `valid` upload dtype: float32 / uint8 / int32 (scan first 64 KB,
// safe for all three candidate dtypes; 0/1 data is unambiguous).
__global__ __launch_bounds__(256) void detect_kernel(const unsigned int* __restrict__ w,
                                                     int* __restrict__ flags) {
    int i = blockIdx.x * blockDim.x + threadIdx.x;   // 64 blocks * 256 = 16384 words
    unsigned int v = w[i];
    unsigned long long mf = __ballot(v == 0x3f800000u);
    unsigned long long mb = __ballot((v & 0xffffff00u) != 0u);
    if ((threadIdx.x & 63) == 0) {
        if (mf) atomicOr(&flags[0], 1);
        if (mb) atomicOr(&flags[1], 1);
    }
}

__global__ __launch_bounds__(256) void convert_valid_kernel(const void* __restrict__ raw,
                                                            const int* __restrict__ flags,
                                                            unsigned char* __restrict__ out) {
    int i = blockIdx.x * blockDim.x + threadIdx.x;
    if (i >= B_ * N_) return;
    unsigned char v;
    if (flags[0])      v = (((const float*)raw)[i] != 0.0f) ? 1 : 0;
    else if (flags[1]) v = (((const unsigned char*)raw)[i] != 0) ? 1 : 0;
    else               v = (((const int*)raw)[i] != 0) ? 1 : 0;
    out[i] = v;
}

// ---------------------------------------------------------------------------
// Phase A (per b): normalize text row + GT visual row, pos_sim, sample_valid.
__global__ __launch_bounds__(256) void phaseA_kernel(const float* __restrict__ text,
                                                     const float* __restrict__ visual,
                                                     const int* __restrict__ gt,
                                                     const unsigned char* __restrict__ valid8,
                                                     float* __restrict__ tn,
                                                     float* __restrict__ gtv,
                                                     float* __restrict__ pos_sim,
                                                     int* __restrict__ svalid,
                                                     int* __restrict__ n_valid) {
    int b = blockIdx.x;
    int tid = threadIdx.x;
    int g = gt[b];
    int gc = min(max(g, 0), N_ - 1);
    const float* trow = text + (size_t)b * D_;
    const float* vrow = visual + ((size_t)b * N_ + gc) * D_;
    float t0 = trow[tid], t1 = trow[tid + 256];
    float v0 = vrow[tid], v1 = vrow[tid + 256];
    float sst = t0 * t0 + t1 * t1;
    float ssv = v0 * v0 + v1 * v1;
    float dot = t0 * v0 + t1 * v1;
    sst = wave_sum(sst);
    ssv = wave_sum(ssv);
    dot = wave_sum(dot);
    __shared__ float r0[4], r1[4], r2[4];
    __shared__ float invt_sh, invv_sh;
    int wave = tid >> 6, lane = tid & 63;
    if (lane == 0) { r0[wave] = sst; r1[wave] = ssv; r2[wave] = dot; }
    __syncthreads();
    if (tid == 0) {
        float st = r0[0] + r0[1] + r0[2] + r0[3];
        float sv = r1[0] + r1[1] + r1[2] + r1[3];
        float d  = r2[0] + r2[1] + r2[2] + r2[3];
        float invt = 1.0f / fmaxf(sqrtf(st), EPS_);
        float invv = 1.0f / fmaxf(sqrtf(sv), EPS_);
        invt_sh = invt;
        invv_sh = invv;
        pos_sim[b] = d * invt * invv * TEMP_INV;
        int s = (g >= 0 && g < N_ && valid8[(size_t)b * N_ + gc]) ? 1 : 0;
        svalid[b] = s;
        if (s) atomicAdd(n_valid, 1);
    }
    __syncthreads();
    float invt = invt_sh, invv = invv_sh;
    tn [(size_t)b * D_ + tid]       = t0 * invt;
    tn [(size_t)b * D_ + tid + 256] = t1 * invt;
    gtv[(size_t)b * D_ + tid]       = v0 * invv;
    gtv[(size_t)b * D_ + tid + 256] = v1 * invv;
}

// ---------------------------------------------------------------------------
// In-sample logits. Grid = B * 4 blocks; each block does 32 rows of one b.
// Quarter-wave dots: 16 lanes per row, 8 float4s/lane, 4-step shfl reduce
// shared across 4 rows per wave. 8 blocks/CU -> latency well hidden.
__global__ __launch_bounds__(256) void insample_kernel(const float* __restrict__ visual,
                                                       const float* __restrict__ tn,
                                                       const int* __restrict__ gt,
                                                       const unsigned char* __restrict__ valid8,
                                                       float* __restrict__ logits_in) {
    int bid = blockIdx.x;
    int b = bid >> 2;
    int tile = bid & 3;
    int tid = threadIdx.x;
    __shared__ float4 tsh4[D_ / 4];
    if (tid < 128) tsh4[tid] = ((const float4*)(tn + (size_t)b * D_))[tid];
    __syncthreads();
    int g = gt[b];
    int gc = min(max(g, 0), N_ - 1);
    int wave = tid >> 6, lane = tid & 63;
    int sub = lane >> 4;      // row within wave (0..3)
    int s = lane & 15;        // lane within quarter-wave
    #pragma unroll
    for (int p = 0; p < 2; ++p) {
        int n = tile * 32 + p * 16 + wave * 4 + sub;
        const float4* vrow = (const float4*)(visual + ((size_t)b * N_ + n) * D_);
        float dot = 0.0f, ss = 0.0f;
        #pragma unroll
        for (int it = 0; it < 8; ++it) {
            float4 v = vrow[s + 16 * it];
            float4 t = tsh4[s + 16 * it];
            dot += v.x * t.x + v.y * t.y + v.z * t.z + v.w * t.w;
            ss  += v.x * v.x + v.y * v.y + v.z * v.z + v.w * v.w;
        }
        #pragma unroll
        for (int off = 8; off; off >>= 1) {
            dot += __shfl_xor(dot, off);
            ss  += __shfl_xor(ss, off);
        }
        if (s == 0) {
            bool m = valid8[(size_t)b * N_ + n] && (n != gc);
            float inv = 1.0f / fmaxf(sqrtf(ss), EPS_);
            logits_in[(size_t)b * N_ + n] = m ? dot * inv * TEMP_INV : NEG_INF_;
        }
    }
}

// ---------------------------------------------------------------------------
// Batch logits: lb[b][j] = tn[b]·gtv[j]/T (masked). Grid = (B/4) * 4 = 512
// blocks; block covers 4 b-rows x 128 j-rows. tn rows staged in LDS (4x reuse
// of each gtv read). Quarter-wave dots, 4 accumulators per lane.
__global__ __launch_bounds__(256) void batch_kernel(const float* __restrict__ gtv,
                                                    const float* __restrict__ tn,
                                                    const int* __restrict__ svalid,
                                                    float* __restrict__ lb) {
    int bid = blockIdx.x;
    int b0 = (bid >> 2) * 4;
    int jbase = (bid & 3) * 128;
    int tid = threadIdx.x;
    __shared__ float4 tsh4[4 * (D_ / 4)];
    #pragma unroll
    for (int idx = tid; idx < 4 * (D_ / 4); idx += 256) {
        int r = idx >> 7, c = idx & 127;
        tsh4[idx] = ((const float4*)tn)[(size_t)(b0 + r) * (D_ / 4) + c];
    }
    __syncthreads();
    int wave = tid >> 6, lane = tid & 63;
    int sub = lane >> 4;
    int s = lane & 15;
    #pragma unroll
    for (int p = 0; p < 8; ++p) {
        int j = jbase + p * 16 + wave * 4 + sub;
        const float4* grow = (const float4*)gtv + (size_t)j * (D_ / 4);
        float a0 = 0.0f, a1 = 0.0f, a2 = 0.0f, a3 = 0.0f;
        #pragma unroll
        for (int it = 0; it < 8; ++it) {
            float4 v  = grow[s + 16 * it];
            float4 t0 = tsh4[0 * 128 + s + 16 * it];
            float4 t1 = tsh4[1 * 128 + s + 16 * it];
            float4 t2 = tsh4[2 * 128 + s + 16 * it];
            float4 t3 = tsh4[3 * 128 + s + 16 * it];
            a0 += v.x * t0.x + v.y * t0.y + v.z * t0.z + v.w * t0.w;
            a1 += v.x * t1.x + v.y * t1.y + v.z * t1.z + v.w * t1.w;
            a2 += v.x * t2.x + v.y * t2.y + v.z * t2.z + v.w * t2.w;
            a3 += v.x * t3.x + v.y * t3.y + v.z * t3.z + v.w * t3.w;
        }
        #pragma unroll
        for (int off = 8; off; off >>= 1) {
            a0 += __shfl_xor(a0, off);
            a1 += __shfl_xor(a1, off);
            a2 += __shfl_xor(a2, off);
            a3 += __shfl_xor(a3, off);
        }
        int sv = svalid[j];
        if (s < 4) {
            float av = (s == 0) ? a0 : (s == 1) ? a1 : (s == 2) ? a2 : a3;
            int brow = b0 + s;
            lb[(size_t)brow * B_ + j] = (sv && j != brow) ? av * TEMP_INV : NEG_INF_;
        }
    }
}

// ---------------------------------------------------------------------------
// Per-row logsumexp over [pos, 128 in-sample, 512 batch] negatives.
__global__ __launch_bounds__(256) void lse_kernel(const float* __restrict__ logits_in,
                                                  const float* __restrict__ lb,
                                                  const float* __restrict__ pos_sim,
                                                  const int* __restrict__ svalid,
                                                  float* __restrict__ accum) {
    int b = blockIdx.x;
    int tid = threadIdx.x;
    float pos = pos_sim[b];
    // gather this thread's up-to-3 negatives (640 total)
    float x0 = (tid < N_) ? logits_in[(size_t)b * N_ + tid]
                          : lb[(size_t)b * B_ + (tid - N_)];
    float x1 = lb[(size_t)b * B_ + (tid + 256 - N_)];
    float x2 = (tid < N_) ? lb[(size_t)b * B_ + (tid + 512 - N_)] : NEG_INF_;
    float lmax = fmaxf(fmaxf(x0, x1), x2);
    for (int off = 32; off; off >>= 1) lmax = fmaxf(lmax, __shfl_xor(lmax, off));
    __shared__ float red[4];
    __shared__ float sh1;
    int wave = tid >> 6, lane = tid & 63;
    if (lane == 0) red[wave] = lmax;
    __syncthreads();
    if (tid == 0) sh1 = fmaxf(fmaxf(red[0], red[1]), fmaxf(red[2], red[3]));
    __syncthreads();
    float maxneg = sh1;
    float m = fmaxf(maxneg, pos);
    float lsum = __expf(x0 - m) + __expf(x1 - m) + ((tid < N_) ? __expf(x2 - m) : 0.0f);
    lsum = wave_sum(lsum);
    __syncthreads();
    if (lane == 0) red[wave] = lsum;
    __syncthreads();
    if (tid == 0) {
        float sum = red[0] + red[1] + red[2] + red[3] + __expf(pos - m);
        float lse = m + logf(sum);
        float loss = lse - pos;
        bool has_neg = maxneg > -1e8f;
        bool contrib = (svalid[b] != 0) && has_neg;
        if (contrib) {
            atomicAdd(&accum[0], loss);
            if (pos >= maxneg) atomicAdd(&accum[1], 1.0f);
        }
    }
}

__global__ void finalize_kernel(const float* __restrict__ accum,
                                const int* __restrict__ n_valid,
                                float* __restrict__ out) {
    if (threadIdx.x == 0 && blockIdx.x == 0) {
        float denom = fmaxf((float)(*n_valid), 1.0f);
        out[0] = accum[0] / denom;
        out[1] = accum[1] / denom;
    }
}

// ---------------------------------------------------------------------------
extern "C" void kernel_launch(void* const* d_in, const int* in_sizes, int n_in,
                              void* d_out, int out_size, void* d_ws, size_t ws_size,
                              hipStream_t stream) {
    const float* text   = (const float*)d_in[0];
    const float* visual = (const float*)d_in[1];
    const void*  valid  = d_in[2];
    const int*   gt     = (const int*)d_in[3];
    float* out = (float*)d_out;

    float* wsf = (float*)d_ws;
    float* tn      = wsf + OFF_TN;
    float* gtv     = wsf + OFF_GTV;
    float* pos_sim = wsf + OFF_POS;
    float* lin     = wsf + OFF_LIN;
    float* lb      = wsf + OFF_LB;
    int*   svalid  = (int*)(wsf + OFF_SV);
    unsigned char* valid8 = (unsigned char*)(wsf + OFF_V8);
    int*   flags   = (int*)(wsf + OFF_SCAL);       // [0],[1]
    int*   n_valid = (int*)(wsf + OFF_SCAL) + 2;   // [2]
    float* accum   = (wsf + OFF_SCAL) + 3;         // [3],[4]

    hipMemsetAsync(wsf + OFF_SCAL, 0, 5 * sizeof(float), stream);

    detect_kernel<<<64, 256, 0, stream>>>((const unsigned int*)valid, flags);
    convert_valid_kernel<<<(B_ * N_ + 255) / 256, 256, 0, stream>>>(valid, flags, valid8);
    phaseA_kernel<<<B_, 256, 0, stream>>>(text, visual, gt, valid8, tn, gtv, pos_sim, svalid, n_valid);
    insample_kernel<<<B_ * 4, 256, 0, stream>>>(visual, tn, gt, valid8, lin);
    batch_kernel<<<B_, 256, 0, stream>>>(gtv, tn, svalid, lb);
    lse_kernel<<<B_, 256, 0, stream>>>(lin, lb, pos_sim, svalid, accum);
    finalize_kernel<<<1, 64, 0, stream>>>(accum, n_valid, out);
}

// Round 4
// 233.696 us; speedup vs baseline: 1.4153x; 1.0070x over previous
//
#include <hip/hip_runtime.h>
#include <hip/hip_bf16.h>
#include <math.h>

// Problem constants (match reference)
constexpr int B_ = 512;
constexpr int N_ = 128;
constexpr int D_ = 512;
constexpr float TEMP_INV = 1.0f / 0.07f;
constexpr float NEG_INF_ = -1e9f;
constexpr float EPS_ = 1e-12f;

// Workspace layout (in floats)
constexpr size_t OFF_TN   = 0;                          // B*D normalized text
constexpr size_t OFF_GTV  = OFF_TN + (size_t)B_ * D_;   // B*D normalized gt visuals
constexpr size_t OFF_POS  = OFF_GTV + (size_t)B_ * D_;  // B   pos_sim
constexpr size_t OFF_LIN  = OFF_POS + B_;               // B*N in-sample logits
constexpr size_t OFF_LB   = OFF_LIN + (size_t)B_ * N_;  // B*B batch logits
constexpr size_t OFF_SV   = OFF_LB + (size_t)B_ * B_;   // B   sample_valid (int)
constexpr size_t OFF_SCAL = OFF_SV + B_;  // flags[2], n_valid, accum[2], done  (7 words)

__device__ __forceinline__ float wave_sum(float v) {
    for (int off = 32; off; off >>= 1) v += __shfl_xor(v, off);
    return v;
}

// ---------------------------------------------------------------------------
// Detect `valid` upload dtype: float32 / uint8 / int32 (scan first 64 KB,
// safe for all three candidate dtypes; 0/1 data is unambiguous):
//   word == 0x3f800000 -> float32 (1.0f); else bits[8,32) set -> uint8; else int32
__global__ __launch_bounds__(256) void detect_kernel(const unsigned int* __restrict__ w,
                                                     int* __restrict__ flags) {
    int i = blockIdx.x * blockDim.x + threadIdx.x;   // 64 blocks * 256 = 16384 words
    unsigned int v = w[i];
    unsigned long long mf = __ballot(v == 0x3f800000u);
    unsigned long long mb = __ballot((v & 0xffffff00u) != 0u);
    if ((threadIdx.x & 63) == 0) {
        if (mf) atomicOr(&flags[0], 1);
        if (mb) atomicOr(&flags[1], 1);
    }
}

__device__ __forceinline__ int decode_valid(const void* raw, int f0, int f1, size_t idx) {
    if (f0) return ((const float*)raw)[idx] != 0.0f;
    if (f1) return ((const unsigned char*)raw)[idx] != 0;
    return ((const int*)raw)[idx] != 0;
}

// ---------------------------------------------------------------------------
// Fused: text-normalize + in-sample logits + GT-row (gtv/pos_sim/svalid).
// Grid = B*4; each block = one b, one 32-row tile. Quarter-wave dots (16
// lanes/row, butterfly reduce -> all lanes hold the full dot/ss, so the
// quarter-wave owning row gc writes the normalized gtv row directly).
__global__ __launch_bounds__(256) void fused_insample_kernel(
        const float* __restrict__ text,
        const float* __restrict__ visual,
        const int* __restrict__ gt,
        const void* __restrict__ valid_raw,
        const int* __restrict__ flags,
        float* __restrict__ tn,
        float* __restrict__ gtv,
        float* __restrict__ pos_sim,
        int* __restrict__ svalid,
        int* __restrict__ n_valid,
        float* __restrict__ lin) {
    int bid = blockIdx.x;
    int b = bid >> 2;
    int tile = bid & 3;
    int tid = threadIdx.x;
    int f0 = flags[0], f1 = flags[1];

    // stage + normalize text row in LDS (redundant across the 4 tiles; 2KB L2 reads)
    __shared__ float4 tsh4[D_ / 4];
    float* tshf = (float*)tsh4;
    const float* trow = text + (size_t)b * D_;
    float t0 = trow[tid], t1 = trow[tid + 256];
    float sst = wave_sum(t0 * t0 + t1 * t1);
    __shared__ float red[4];
    __shared__ float invt_sh;
    int wave = tid >> 6, lane = tid & 63;
    if (lane == 0) red[wave] = sst;
    __syncthreads();
    if (tid == 0) invt_sh = 1.0f / fmaxf(sqrtf(red[0] + red[1] + red[2] + red[3]), EPS_);
    __syncthreads();
    float invt = invt_sh;
    t0 *= invt; t1 *= invt;
    tshf[tid] = t0; tshf[tid + 256] = t1;
    if (tile == 0) {                       // one tile publishes tn for batch_kernel
        tn[(size_t)b * D_ + tid]       = t0;
        tn[(size_t)b * D_ + tid + 256] = t1;
    }
    __syncthreads();

    int g = gt[b];
    int gc = min(max(g, 0), N_ - 1);
    int sub = lane >> 4;      // row within wave (0..3)
    int s = lane & 15;        // lane within quarter-wave

    #pragma unroll
    for (int p = 0; p < 2; ++p) {
        int n = tile * 32 + p * 16 + wave * 4 + sub;
        const float4* vrow = (const float4*)(visual + ((size_t)b * N_ + n) * D_);
        float dot = 0.0f, ss = 0.0f;
        #pragma unroll
        for (int it = 0; it < 8; ++it) {
            float4 v = vrow[s + 16 * it];
            float4 t = tsh4[s + 16 * it];
            dot += v.x * t.x + v.y * t.y + v.z * t.z + v.w * t.w;
            ss  += v.x * v.x + v.y * v.y + v.z * v.z + v.w * v.w;
        }
        #pragma unroll
        for (int off = 8; off; off >>= 1) {   // butterfly: all 16 lanes get result
            dot += __shfl_xor(dot, off);
            ss  += __shfl_xor(ss, off);
        }
        float inv = 1.0f / fmaxf(sqrtf(ss), EPS_);
        if (s == 0) {
            int vb = decode_valid(valid_raw, f0, f1, (size_t)b * N_ + n);
            bool m = vb && (n != gc);
            lin[(size_t)b * N_ + n] = m ? dot * inv * TEMP_INV : NEG_INF_;
            if (n == gc) {
                pos_sim[b] = dot * inv * TEMP_INV;
                int sv = (g >= 0 && g < N_ && vb) ? 1 : 0;
                svalid[b] = sv;
                if (sv) atomicAdd(n_valid, 1);
            }
        }
        if (n == gc) {   // whole quarter-wave writes the normalized GT row (L2-hot re-read)
            float4* gdst = (float4*)(gtv + (size_t)b * D_);
            #pragma unroll
            for (int it = 0; it < 8; ++it) {
                float4 v = vrow[s + 16 * it];
                gdst[s + 16 * it] = make_float4(v.x * inv, v.y * inv, v.z * inv, v.w * inv);
            }
        }
    }
}

// ---------------------------------------------------------------------------
// Batch logits: lb[b][j] = tn[b]·gtv[j]/T (masked). 512 blocks; block covers
// 4 b-rows x 128 j-rows; tn rows staged in LDS (4x reuse of each gtv read).
__global__ __launch_bounds__(256) void batch_kernel(const float* __restrict__ gtv,
                                                    const float* __restrict__ tn,
                                                    const int* __restrict__ svalid,
                                                    float* __restrict__ lb) {
    int bid = blockIdx.x;
    int b0 = (bid >> 2) * 4;
    int jbase = (bid & 3) * 128;
    int tid = threadIdx.x;
    __shared__ float4 tsh4[4 * (D_ / 4)];
    #pragma unroll
    for (int idx = tid; idx < 4 * (D_ / 4); idx += 256) {
        int r = idx >> 7, c = idx & 127;
        tsh4[idx] = ((const float4*)tn)[(size_t)(b0 + r) * (D_ / 4) + c];
    }
    __syncthreads();
    int wave = tid >> 6, lane = tid & 63;
    int sub = lane >> 4;
    int s = lane & 15;
    #pragma unroll
    for (int p = 0; p < 8; ++p) {
        int j = jbase + p * 16 + wave * 4 + sub;
        const float4* grow = (const float4*)gtv + (size_t)j * (D_ / 4);
        float a0 = 0.0f, a1 = 0.0f, a2 = 0.0f, a3 = 0.0f;
        #pragma unroll
        for (int it = 0; it < 8; ++it) {
            float4 v  = grow[s + 16 * it];
            float4 t0 = tsh4[0 * 128 + s + 16 * it];
            float4 t1 = tsh4[1 * 128 + s + 16 * it];
            float4 t2 = tsh4[2 * 128 + s + 16 * it];
            float4 t3 = tsh4[3 * 128 + s + 16 * it];
            a0 += v.x * t0.x + v.y * t0.y + v.z * t0.z + v.w * t0.w;
            a1 += v.x * t1.x + v.y * t1.y + v.z * t1.z + v.w * t1.w;
            a2 += v.x * t2.x + v.y * t2.y + v.z * t2.z + v.w * t2.w;
            a3 += v.x * t3.x + v.y * t3.y + v.z * t3.z + v.w * t3.w;
        }
        #pragma unroll
        for (int off = 8; off; off >>= 1) {
            a0 += __shfl_xor(a0, off);
            a1 += __shfl_xor(a1, off);
            a2 += __shfl_xor(a2, off);
            a3 += __shfl_xor(a3, off);
        }
        int sv = svalid[j];
        if (s < 4) {
            float av = (s == 0) ? a0 : (s == 1) ? a1 : (s == 2) ? a2 : a3;
            int brow = b0 + s;
            lb[(size_t)brow * B_ + j] = (sv && j != brow) ? av * TEMP_INV : NEG_INF_;
        }
    }
}

// ---------------------------------------------------------------------------
// Per-row logsumexp over [pos, 128 in-sample, 512 batch]; last block finalizes.
__global__ __launch_bounds__(256) void lse_kernel(const float* __restrict__ logits_in,
                                                  const float* __restrict__ lb,
                                                  const float* __restrict__ pos_sim,
                                                  const int* __restrict__ svalid,
                                                  float* __restrict__ accum,
                                                  int* __restrict__ n_valid,
                                                  int* __restrict__ done,
                                                  float* __restrict__ out) {
    int b = blockIdx.x;
    int tid = threadIdx.x;
    float pos = pos_sim[b];
    float x0 = (tid < N_) ? logits_in[(size_t)b * N_ + tid]
                          : lb[(size_t)b * B_ + (tid - N_)];
    float x1 = lb[(size_t)b * B_ + (tid + 256 - N_)];
    float x2 = (tid < N_) ? lb[(size_t)b * B_ + (tid + 512 - N_)] : NEG_INF_;
    float lmax = fmaxf(fmaxf(x0, x1), x2);
    for (int off = 32; off; off >>= 1) lmax = fmaxf(lmax, __shfl_xor(lmax, off));
    __shared__ float red[4];
    __shared__ float sh1;
    int wave = tid >> 6, lane = tid & 63;
    if (lane == 0) red[wave] = lmax;
    __syncthreads();
    if (tid == 0) sh1 = fmaxf(fmaxf(red[0], red[1]), fmaxf(red[2], red[3]));
    __syncthreads();
    float maxneg = sh1;
    float m = fmaxf(maxneg, pos);
    float lsum = __expf(x0 - m) + __expf(x1 - m) + ((tid < N_) ? __expf(x2 - m) : 0.0f);
    lsum = wave_sum(lsum);
    __syncthreads();
    if (lane == 0) red[wave] = lsum;
    __syncthreads();
    if (tid == 0) {
        float sum = red[0] + red[1] + red[2] + red[3] + __expf(pos - m);
        float lse = m + logf(sum);
        float loss = lse - pos;
        bool has_neg = maxneg > -1e8f;
        bool contrib = (svalid[b] != 0) && has_neg;
        if (contrib) {
            atomicAdd(&accum[0], loss);
            if (pos >= maxneg) atomicAdd(&accum[1], 1.0f);
        }
        __threadfence();
        int prev = atomicAdd(done, 1);
        if (prev == B_ - 1) {     // last block finalizes
            float total = atomicAdd(&accum[0], 0.0f);   // coherent read via RMW
            float acc   = atomicAdd(&accum[1], 0.0f);
            int   nv    = atomicAdd(n_valid, 0);
            float denom = fmaxf((float)nv, 1.0f);
            out[0] = total / denom;
            out[1] = acc / denom;
        }
    }
}

// ---------------------------------------------------------------------------
extern "C" void kernel_launch(void* const* d_in, const int* in_sizes, int n_in,
                              void* d_out, int out_size, void* d_ws, size_t ws_size,
                              hipStream_t stream) {
    const float* text   = (const float*)d_in[0];
    const float* visual = (const float*)d_in[1];
    const void*  valid  = d_in[2];
    const int*   gt     = (const int*)d_in[3];
    float* out = (float*)d_out;

    float* wsf = (float*)d_ws;
    float* tn      = wsf + OFF_TN;
    float* gtv     = wsf + OFF_GTV;
    float* pos_sim = wsf + OFF_POS;
    float* lin     = wsf + OFF_LIN;
    float* lb      = wsf + OFF_LB;
    int*   svalid  = (int*)(wsf + OFF_SV);
    int*   flags   = (int*)(wsf + OFF_SCAL);       // [0],[1]
    int*   n_valid = (int*)(wsf + OFF_SCAL) + 2;   // [2]
    float* accum   = (wsf + OFF_SCAL) + 3;         // [3],[4]
    int*   done    = (int*)(wsf + OFF_SCAL) + 5;   // [5]

    hipMemsetAsync(wsf + OFF_SCAL, 0, 6 * sizeof(float), stream);

    detect_kernel<<<64, 256, 0, stream>>>((const unsigned int*)valid, flags);
    fused_insample_kernel<<<B_ * 4, 256, 0, stream>>>(text, visual, gt, valid, flags,
                                                      tn, gtv, pos_sim, svalid, n_valid, lin);
    batch_kernel<<<B_, 256, 0, stream>>>(gtv, tn, svalid, lb);
    lse_kernel<<<B_, 256, 0, stream>>>(lin, lb, pos_sim, svalid, accum, n_valid, done, out);
}

// Round 5
// 227.807 us; speedup vs baseline: 1.4519x; 1.0259x over previous
//
#include <hip/hip_runtime.h>
#include <hip/hip_bf16.h>
#include <math.h>

// Problem constants (match reference)
constexpr int B_ = 512;
constexpr int N_ = 128;
constexpr int D_ = 512;
constexpr float TEMP_INV = 1.0f / 0.07f;
constexpr float NEG_INF_ = -1e9f;
constexpr float EPS_ = 1e-12f;

// Workspace layout (in floats)
constexpr size_t OFF_TN   = 0;                          // B*D normalized text
constexpr size_t OFF_GTV  = OFF_TN + (size_t)B_ * D_;   // B*D normalized gt visuals
constexpr size_t OFF_POS  = OFF_GTV + (size_t)B_ * D_;  // B   pos_sim
constexpr size_t OFF_LIN  = OFF_POS + B_;               // B*N in-sample logits
constexpr size_t OFF_LB   = OFF_LIN + (size_t)B_ * N_;  // B*B batch logits
constexpr size_t OFF_SV   = OFF_LB + (size_t)B_ * B_;   // B   sample_valid (int)
constexpr size_t OFF_SCAL = OFF_SV + B_;                // accum[2], done (3 words)

__device__ __forceinline__ float wave_sum(float v) {
    for (int off = 32; off; off >>= 1) v += __shfl_xor(v, off);
    return v;
}

// Wave-local dtype detection for `valid`: scan first 64 words (L1-broadcast).
// 0/1 data is unambiguous: word==0x3f800000 -> float32; else any bits in
// [8,32) -> uint8 bytes; else int32. P(miss) ~ 0.1^64.
__device__ __forceinline__ void detect_flags(const void* raw, int lane, int& f0, int& f1) {
    unsigned int v = ((const unsigned int*)raw)[lane];
    f0 = (__ballot(v == 0x3f800000u) != 0ull) ? 1 : 0;
    f1 = (__ballot((v & 0xffffff00u) != 0u) != 0ull) ? 1 : 0;
}

__device__ __forceinline__ int decode_valid(const void* raw, int f0, int f1, size_t idx) {
    if (f0) return ((const float*)raw)[idx] != 0.0f;
    if (f1) return ((const unsigned char*)raw)[idx] != 0;
    return ((const int*)raw)[idx] != 0;
}

// ---------------------------------------------------------------------------
// Fused: dtype-detect + text-normalize + in-sample logits + GT-row
// (gtv/pos_sim/svalid) + scalar zero-init. Grid = B*4; block = one b, one
// 32-row tile. Quarter-wave dots: 16 lanes/row, butterfly reduce so all 16
// lanes hold the full dot/ss (the quarter-wave owning row gc writes the
// normalized gtv row directly from registers).
__global__ __launch_bounds__(256) void fused_insample_kernel(
        const float* __restrict__ text,
        const float* __restrict__ visual,
        const int* __restrict__ gt,
        const void* __restrict__ valid_raw,
        float* __restrict__ tn,
        float* __restrict__ gtv,
        float* __restrict__ pos_sim,
        int* __restrict__ svalid,
        float* __restrict__ scal,   // accum[2], done — zeroed here for lse
        float* __restrict__ lin) {
    int bid = blockIdx.x;
    int b = bid >> 2;
    int tile = bid & 3;
    int tid = threadIdx.x;
    int wave = tid >> 6, lane = tid & 63;

    if (bid == 0 && tid < 3) scal[tid] = 0.0f;   // accum[0..1], done (lse runs later)

    int f0, f1;
    detect_flags(valid_raw, lane, f0, f1);       // wave-uniform, no sync needed

    // stage + normalize text row in LDS (4x redundant across tiles; L2-hot)
    __shared__ float4 tsh4[D_ / 4];
    float* tshf = (float*)tsh4;
    const float* trow = text + (size_t)b * D_;
    float t0 = trow[tid], t1 = trow[tid + 256];
    float sst = wave_sum(t0 * t0 + t1 * t1);
    __shared__ float red[4];
    __shared__ float invt_sh;
    if (lane == 0) red[wave] = sst;
    __syncthreads();
    if (tid == 0) invt_sh = 1.0f / fmaxf(sqrtf(red[0] + red[1] + red[2] + red[3]), EPS_);
    __syncthreads();
    float invt = invt_sh;
    t0 *= invt; t1 *= invt;
    tshf[tid] = t0; tshf[tid + 256] = t1;
    if (tile == 0) {                              // one tile publishes tn
        tn[(size_t)b * D_ + tid]       = t0;
        tn[(size_t)b * D_ + tid + 256] = t1;
    }
    __syncthreads();

    int g = gt[b];
    int gc = min(max(g, 0), N_ - 1);
    int sub = lane >> 4;      // row within wave (0..3)
    int s = lane & 15;        // lane within quarter-wave

    #pragma unroll
    for (int p = 0; p < 2; ++p) {
        int n = tile * 32 + p * 16 + wave * 4 + sub;
        const float4* vrow = (const float4*)(visual + ((size_t)b * N_ + n) * D_);
        float dot = 0.0f, ss = 0.0f;
        #pragma unroll
        for (int it = 0; it < 8; ++it) {
            float4 v = vrow[s + 16 * it];
            float4 t = tsh4[s + 16 * it];
            dot += v.x * t.x + v.y * t.y + v.z * t.z + v.w * t.w;
            ss  += v.x * v.x + v.y * v.y + v.z * v.z + v.w * v.w;
        }
        #pragma unroll
        for (int off = 8; off; off >>= 1) {       // butterfly: all 16 lanes get result
            dot += __shfl_xor(dot, off);
            ss  += __shfl_xor(ss, off);
        }
        float inv = 1.0f / fmaxf(sqrtf(ss), EPS_);
        if (s == 0) {
            int vb = decode_valid(valid_raw, f0, f1, (size_t)b * N_ + n);
            bool m = vb && (n != gc);
            lin[(size_t)b * N_ + n] = m ? dot * inv * TEMP_INV : NEG_INF_;
            if (n == gc) {
                pos_sim[b] = dot * inv * TEMP_INV;
                svalid[b] = (g >= 0 && g < N_ && vb) ? 1 : 0;
            }
        }
        if (n == gc) {   // quarter-wave writes normalized GT row from registers
            float4* gdst = (float4*)(gtv + (size_t)b * D_);
            #pragma unroll
            for (int it = 0; it < 8; ++it) {
                float4 v = vrow[s + 16 * it];
                gdst[s + 16 * it] = make_float4(v.x * inv, v.y * inv, v.z * inv, v.w * inv);
            }
        }
    }
}

// ---------------------------------------------------------------------------
// Batch logits: lb[b][j] = tn[b]·gtv[j]/T (masked). 512 blocks; block covers
// 4 b-rows x 128 j-rows; tn rows staged in LDS (4x reuse of each gtv read).
__global__ __launch_bounds__(256) void batch_kernel(const float* __restrict__ gtv,
                                                    const float* __restrict__ tn,
                                                    const int* __restrict__ svalid,
                                                    float* __restrict__ lb) {
    int bid = blockIdx.x;
    int b0 = (bid >> 2) * 4;
    int jbase = (bid & 3) * 128;
    int tid = threadIdx.x;
    __shared__ float4 tsh4[4 * (D_ / 4)];
    #pragma unroll
    for (int idx = tid; idx < 4 * (D_ / 4); idx += 256) {
        int r = idx >> 7, c = idx & 127;
        tsh4[idx] = ((const float4*)tn)[(size_t)(b0 + r) * (D_ / 4) + c];
    }
    __syncthreads();
    int wave = tid >> 6, lane = tid & 63;
    int sub = lane >> 4;
    int s = lane & 15;
    #pragma unroll
    for (int p = 0; p < 8; ++p) {
        int j = jbase + p * 16 + wave * 4 + sub;
        const float4* grow = (const float4*)gtv + (size_t)j * (D_ / 4);
        float a0 = 0.0f, a1 = 0.0f, a2 = 0.0f, a3 = 0.0f;
        #pragma unroll
        for (int it = 0; it < 8; ++it) {
            float4 v  = grow[s + 16 * it];
            float4 t0 = tsh4[0 * 128 + s + 16 * it];
            float4 t1 = tsh4[1 * 128 + s + 16 * it];
            float4 t2 = tsh4[2 * 128 + s + 16 * it];
            float4 t3 = tsh4[3 * 128 + s + 16 * it];
            a0 += v.x * t0.x + v.y * t0.y + v.z * t0.z + v.w * t0.w;
            a1 += v.x * t1.x + v.y * t1.y + v.z * t1.z + v.w * t1.w;
            a2 += v.x * t2.x + v.y * t2.y + v.z * t2.z + v.w * t2.w;
            a3 += v.x * t3.x + v.y * t3.y + v.z * t3.z + v.w * t3.w;
        }
        #pragma unroll
        for (int off = 8; off; off >>= 1) {
            a0 += __shfl_xor(a0, off);
            a1 += __shfl_xor(a1, off);
            a2 += __shfl_xor(a2, off);
            a3 += __shfl_xor(a3, off);
        }
        int sv = svalid[j];
        if (s < 4) {
            float av = (s == 0) ? a0 : (s == 1) ? a1 : (s == 2) ? a2 : a3;
            int brow = b0 + s;
            lb[(size_t)brow * B_ + j] = (sv && j != brow) ? av * TEMP_INV : NEG_INF_;
        }
    }
}

// ---------------------------------------------------------------------------
// Per-row logsumexp over [pos, 128 in-sample, 512 batch]; the LAST finishing
// block sums svalid and writes the two outputs (no separate finalize node).
__global__ __launch_bounds__(256) void lse_kernel(const float* __restrict__ logits_in,
                                                  const float* __restrict__ lb,
                                                  const float* __restrict__ pos_sim,
                                                  const int* __restrict__ svalid,
                                                  float* __restrict__ accum,
                                                  int* __restrict__ done,
                                                  float* __restrict__ out) {
    int b = blockIdx.x;
    int tid = threadIdx.x;
    int wave = tid >> 6, lane = tid & 63;
    float pos = pos_sim[b];
    float x0 = (tid < N_) ? logits_in[(size_t)b * N_ + tid]
                          : lb[(size_t)b * B_ + (tid - N_)];
    float x1 = lb[(size_t)b * B_ + (tid + 256 - N_)];
    float x2 = (tid < N_) ? lb[(size_t)b * B_ + (tid + 512 - N_)] : NEG_INF_;
    float lmax = fmaxf(fmaxf(x0, x1), x2);
    for (int off = 32; off; off >>= 1) lmax = fmaxf(lmax, __shfl_xor(lmax, off));
    __shared__ float red[4];
    __shared__ float sh1;
    if (lane == 0) red[wave] = lmax;
    __syncthreads();
    if (tid == 0) sh1 = fmaxf(fmaxf(red[0], red[1]), fmaxf(red[2], red[3]));
    __syncthreads();
    float maxneg = sh1;
    float m = fmaxf(maxneg, pos);
    float lsum = __expf(x0 - m) + __expf(x1 - m) + ((tid < N_) ? __expf(x2 - m) : 0.0f);
    lsum = wave_sum(lsum);
    __syncthreads();
    if (lane == 0) red[wave] = lsum;
    __syncthreads();
    __shared__ int is_last;
    if (tid == 0) {
        float sum = red[0] + red[1] + red[2] + red[3] + __expf(pos - m);
        float lse = m + logf(sum);
        float loss = lse - pos;
        bool has_neg = maxneg > -1e8f;
        bool contrib = (svalid[b] != 0) && has_neg;
        if (contrib) {
            atomicAdd(&accum[0], loss);
            if (pos >= maxneg) atomicAdd(&accum[1], 1.0f);
        }
        __threadfence();
        int prev = atomicAdd(done, 1);
        is_last = (prev == B_ - 1) ? 1 : 0;
    }
    __syncthreads();
    if (is_last) {
        // all 256 threads sum svalid (written two dispatches ago — coherent)
        int v = svalid[tid] + svalid[tid + 256];
        for (int off = 32; off; off >>= 1) v += __shfl_xor(v, off);
        __shared__ int ired[4];
        if (lane == 0) ired[wave] = v;
        __syncthreads();
        if (tid == 0) {
            int nv = ired[0] + ired[1] + ired[2] + ired[3];
            float total = atomicAdd(&accum[0], 0.0f);  // coherent read via RMW
            float acc   = atomicAdd(&accum[1], 0.0f);
            float denom = fmaxf((float)nv, 1.0f);
            out[0] = total / denom;
            out[1] = acc / denom;
        }
    }
}

// ---------------------------------------------------------------------------
extern "C" void kernel_launch(void* const* d_in, const int* in_sizes, int n_in,
                              void* d_out, int out_size, void* d_ws, size_t ws_size,
                              hipStream_t stream) {
    const float* text   = (const float*)d_in[0];
    const float* visual = (const float*)d_in[1];
    const void*  valid  = d_in[2];
    const int*   gt     = (const int*)d_in[3];
    float* out = (float*)d_out;

    float* wsf = (float*)d_ws;
    float* tn      = wsf + OFF_TN;
    float* gtv     = wsf + OFF_GTV;
    float* pos_sim = wsf + OFF_POS;
    float* lin     = wsf + OFF_LIN;
    float* lb      = wsf + OFF_LB;
    int*   svalid  = (int*)(wsf + OFF_SV);
    float* scal    = wsf + OFF_SCAL;               // accum[0..1], done
    float* accum   = scal;
    int*   done    = (int*)(scal + 2);

    fused_insample_kernel<<<B_ * 4, 256, 0, stream>>>(text, visual, gt, valid,
                                                      tn, gtv, pos_sim, svalid, scal, lin);
    batch_kernel<<<B_, 256, 0, stream>>>(gtv, tn, svalid, lb);
    lse_kernel<<<B_, 256, 0, stream>>>(lin, lb, pos_sim, svalid, accum, done, out);
}